// Round 3
// baseline (698.985 us; speedup 1.0000x reference)
//
#include <hip/hip_runtime.h>

typedef unsigned short u16;
typedef unsigned int   u32;
typedef short bf16x8 __attribute__((ext_vector_type(8)));   // 8 bf16 (4 VGPRs)
typedef unsigned short u16x8 __attribute__((ext_vector_type(8)));
typedef float f32x4 __attribute__((ext_vector_type(4)));

__device__ __forceinline__ float bf2f(u16 u) {
    u32 x = ((u32)u) << 16;
    return __builtin_bit_cast(float, x);
}
__device__ __forceinline__ u16 f2bf(float f) {
    u32 u = __builtin_bit_cast(u32, f);
    u += 0x7fffu + ((u >> 16) & 1u);   // RNE
    return (u16)(u >> 16);
}
__device__ __forceinline__ float gelu_f(float x) {
    return 0.5f * x * (1.f + tanhf(0.7978845608028654f * (x + 0.044715f * x * x * x)));
}

// ---------------------------------------------------------------- dtype sniff
// flag=1 if inputs are f32, 0 if bf16. Samples low u16 of u32 words of x:
// bf16 data -> low half is a bf16 value, exponent in sane range; f32 data ->
// low half is mantissa bits, uniform -> ~72% absurd exponents.
__global__ void sniff_kernel(const u32* __restrict__ p, int* __restrict__ flag) {
    const int i = threadIdx.x;                    // 0..63
    const u32 w = p[i * 8191 + 5];
    const u32 e = (w >> 7) & 0xFF;
    const bool absurd = (e >= 1 && e <= 90) || (e >= 160 && e <= 254);
    const unsigned long long m = __ballot(absurd);
    if (i == 0) *flag = (__popcll(m) >= 8) ? 1 : 0;
}

// ---------------------------------------------------------------- convert
__global__ void cvt_kernel(const void* __restrict__ src, u16* __restrict__ dst,
                           int n, const int* __restrict__ flag) {
    const int f = *flag;
    const int idx = blockIdx.x * blockDim.x + threadIdx.x;
    const int stride = gridDim.x * blockDim.x;
    if (f) {
        const float* s = (const float*)src;
        for (int i = idx; i < n; i += stride) dst[i] = f2bf(s[i]);
    } else {
        const u16* s = (const u16*)src;
        for (int i = idx; i < n; i += stride) dst[i] = s[i];
    }
}

// ---------------------------------------------------------------- transpose+convert
// src[Kd][Nd] (f32 or bf16 per flag) -> dst[Nd][Kd] bf16. grid (Nd/32, Kd/32).
__global__ __launch_bounds__(256) void transpose_cv(const void* __restrict__ src,
                                                    u16* __restrict__ dst,
                                                    int Kd, int Nd,
                                                    const int* __restrict__ flag) {
    const int f = *flag;
    __shared__ u16 t[32][33];
    const int tx = threadIdx.x & 31, ty = threadIdx.x >> 5;   // ty 0..7
    const int x  = blockIdx.x * 32 + tx;
    const int y0 = blockIdx.y * 32;
#pragma unroll
    for (int j = 0; j < 4; ++j) {
        const long idx = (long)(y0 + ty + j * 8) * Nd + x;
        t[ty + j * 8][tx] = f ? f2bf(((const float*)src)[idx]) : ((const u16*)src)[idx];
    }
    __syncthreads();
    const int xo = blockIdx.y * 32 + tx;
#pragma unroll
    for (int j = 0; j < 4; ++j)
        dst[(long)(blockIdx.x * 32 + ty + j * 8) * Kd + xo] = t[tx][ty + j * 8];
}

// ---------------------------------------------------------------- layernorm (in-place, bf16)
__global__ __launch_bounds__(256) void ln_kernel(u16* __restrict__ x,
                                                 const u16* __restrict__ g,
                                                 const u16* __restrict__ bta) {
    const int tid = threadIdx.x;
    u16* p = x + (long)blockIdx.x * 1024;
    float v[4];
    float s = 0.f, s2 = 0.f;
#pragma unroll
    for (int i = 0; i < 4; ++i) {
        v[i] = bf2f(p[tid + i * 256]);
        s += v[i]; s2 += v[i] * v[i];
    }
#pragma unroll
    for (int off = 32; off; off >>= 1) {
        s  += __shfl_xor(s, off, 64);
        s2 += __shfl_xor(s2, off, 64);
    }
    __shared__ float ps[8];
    if ((tid & 63) == 0) { ps[(tid >> 6) * 2] = s; ps[(tid >> 6) * 2 + 1] = s2; }
    __syncthreads();
    s  = ps[0] + ps[2] + ps[4] + ps[6];
    s2 = ps[1] + ps[3] + ps[5] + ps[7];
    const float mu  = s * (1.f / 1024.f);
    const float var = s2 * (1.f / 1024.f) - mu * mu;
    const float rs  = rsqrtf(var + 1e-5f);
#pragma unroll
    for (int i = 0; i < 4; ++i) {
        const int c = tid + i * 256;
        p[c] = f2bf((v[i] - mu) * rs * bf2f(g[c]) + bf2f(bta[c]));
    }
}

// ---------------------------------------------------------------- final layernorm
// reads bf16 xin, writes d_out as f32 (flag=1) or bf16 (flag=0).
__global__ __launch_bounds__(256) void ln_out_kernel(const u16* __restrict__ xin,
                                                     const u16* __restrict__ g,
                                                     const u16* __restrict__ bta,
                                                     void* __restrict__ out,
                                                     const int* __restrict__ flag) {
    const int tid = threadIdx.x;
    const u16* p = xin + (long)blockIdx.x * 1024;
    float v[4];
    float s = 0.f, s2 = 0.f;
#pragma unroll
    for (int i = 0; i < 4; ++i) {
        v[i] = bf2f(p[tid + i * 256]);
        s += v[i]; s2 += v[i] * v[i];
    }
#pragma unroll
    for (int off = 32; off; off >>= 1) {
        s  += __shfl_xor(s, off, 64);
        s2 += __shfl_xor(s2, off, 64);
    }
    __shared__ float ps[8];
    if ((tid & 63) == 0) { ps[(tid >> 6) * 2] = s; ps[(tid >> 6) * 2 + 1] = s2; }
    __syncthreads();
    s  = ps[0] + ps[2] + ps[4] + ps[6];
    s2 = ps[1] + ps[3] + ps[5] + ps[7];
    const float mu  = s * (1.f / 1024.f);
    const float var = s2 * (1.f / 1024.f) - mu * mu;
    const float rs  = rsqrtf(var + 1e-5f);
    const int f = *flag;
    if (f) {
        float* o = (float*)out + (long)blockIdx.x * 1024;
#pragma unroll
        for (int i = 0; i < 4; ++i) {
            const int c = tid + i * 256;
            o[c] = (v[i] - mu) * rs * bf2f(g[c]) + bf2f(bta[c]);
        }
    } else {
        u16* o = (u16*)out + (long)blockIdx.x * 1024;
#pragma unroll
        for (int i = 0; i < 4; ++i) {
            const int c = tid + i * 256;
            o[c] = f2bf((v[i] - mu) * rs * bf2f(g[c]) + bf2f(bta[c]));
        }
    }
}

// ---------------------------------------------------------------- GEMM
// C[M,N] = A[M,K] @ W[K,N] (+bias, +res / gelu), W pre-transposed Bt[N,K].
// 128x128 tile, 4 waves 2x2, 4x4 16x16x32 MFMA per wave, BK=32. bf16.
#define LDSTRIDE 40   // 32 + 8 pad, keeps 16B align
template <int EPI>    // 0 = bias, 1 = bias+residual, 2 = bias+gelu
__global__ __launch_bounds__(256) void gemm_bt(const u16* __restrict__ A,
                                               const u16* __restrict__ Bt,
                                               const u16* __restrict__ bias,
                                               const u16* __restrict__ res,
                                               u16* __restrict__ C,
                                               int N, int K) {
    const int tid  = threadIdx.x;
    const int wave = tid >> 6, lane = tid & 63;
    const int quad = lane >> 4, l16 = lane & 15;
    const int wm = wave >> 1, wn = wave & 1;
    const int m0 = blockIdx.y * 128, n0 = blockIdx.x * 128;

    __shared__ u16 Al[128 * LDSTRIDE];
    __shared__ u16 Bl[128 * LDSTRIDE];

    f32x4 acc[4][4];
#pragma unroll
    for (int i = 0; i < 4; ++i)
#pragma unroll
        for (int j = 0; j < 4; ++j) acc[i][j] = (f32x4){0.f, 0.f, 0.f, 0.f};

    const int c0 = tid, c1 = tid + 256;           // 512 chunks of 8 elems
    const int ar0 = c0 >> 2, ak0 = (c0 & 3) * 8;
    const int ar1 = c1 >> 2, ak1 = (c1 & 3) * 8;

    for (int kt = 0; kt < K; kt += 32) {
        uint4 a0 = *(const uint4*)(A  + (long)(m0 + ar0) * K + kt + ak0);
        uint4 a1 = *(const uint4*)(A  + (long)(m0 + ar1) * K + kt + ak1);
        uint4 b0 = *(const uint4*)(Bt + (long)(n0 + ar0) * K + kt + ak0);
        uint4 b1 = *(const uint4*)(Bt + (long)(n0 + ar1) * K + kt + ak1);
        __syncthreads();                    // prev tile's reads done
        *(uint4*)(&Al[ar0 * LDSTRIDE + ak0]) = a0;
        *(uint4*)(&Al[ar1 * LDSTRIDE + ak1]) = a1;
        *(uint4*)(&Bl[ar0 * LDSTRIDE + ak0]) = b0;
        *(uint4*)(&Bl[ar1 * LDSTRIDE + ak1]) = b1;
        __syncthreads();                    // tile staged

        bf16x8 af[4], bfr[4];
#pragma unroll
        for (int mt = 0; mt < 4; ++mt)
            af[mt] = *(const bf16x8*)(&Al[(wm * 64 + mt * 16 + l16) * LDSTRIDE + quad * 8]);
#pragma unroll
        for (int nt = 0; nt < 4; ++nt)
            bfr[nt] = *(const bf16x8*)(&Bl[(wn * 64 + nt * 16 + l16) * LDSTRIDE + quad * 8]);
#pragma unroll
        for (int mt = 0; mt < 4; ++mt)
#pragma unroll
            for (int nt = 0; nt < 4; ++nt)
                acc[mt][nt] = __builtin_amdgcn_mfma_f32_16x16x32_bf16(af[mt], bfr[nt],
                                                                      acc[mt][nt], 0, 0, 0);
    }

    // D row = quad*4+r, col = l16 (m89/m91-verified)
#pragma unroll
    for (int mt = 0; mt < 4; ++mt)
#pragma unroll
        for (int r = 0; r < 4; ++r) {
            const long row = m0 + wm * 64 + mt * 16 + quad * 4 + r;
#pragma unroll
            for (int nt = 0; nt < 4; ++nt) {
                const int col = n0 + wn * 64 + nt * 16 + l16;
                float v = acc[mt][nt][r] + bf2f(bias[col]);
                if constexpr (EPI == 1) v += bf2f(res[row * N + col]);
                if constexpr (EPI == 2) v = gelu_f(v);
                C[row * N + col] = f2bf(v);
            }
        }
}

// ---------------------------------------------------------------- attention
// Flash-style fused attention, hd=64. One block = 64 q rows of one (b,h);
// 4 waves x 16 q rows. Output merged-heads into [tokens,1024] at col h*64.
#define KSTR 72   // 64 + 8 pad
#define MASKV -3.0e4f
template <bool CAUSAL>
__global__ __launch_bounds__(256) void attn_kernel(const u16* __restrict__ Qb,
                                                   const u16* __restrict__ Kb,
                                                   const u16* __restrict__ Vb,
                                                   u16* __restrict__ Ob,
                                                   int qstride, int kvstride, int S) {
    const int tid  = threadIdx.x;
    const int wave = tid >> 6, lane = tid & 63;
    const int quad = lane >> 4, l16 = lane & 15;
    const int h = blockIdx.y, b = blockIdx.z;
    const int qt0 = blockIdx.x * 64;
    const long tokbase = (long)b * S;

    __shared__ u16 K_lds[64 * KSTR];
    __shared__ u16 Vt_lds[64 * KSTR];   // [d][key]
    __shared__ u16 P_lds[64 * KSTR];    // [qrow(64)][key]

    // Q fragments (A-operand: m=l16, k=quad*8+j)
    const u16* qrow = Qb + (tokbase + qt0 + wave * 16 + l16) * qstride + h * 64;
    bf16x8 qf[2];
    qf[0] = *(const bf16x8*)(qrow + quad * 8);
    qf[1] = *(const bf16x8*)(qrow + 32 + quad * 8);

    f32x4 acc[4];
#pragma unroll
    for (int i = 0; i < 4; ++i) acc[i] = (f32x4){0.f, 0.f, 0.f, 0.f};
    float mrow[4], lrow[4];
#pragma unroll
    for (int r = 0; r < 4; ++r) { mrow[r] = MASKV; lrow[r] = 0.f; }

    const int nkt = CAUSAL ? (blockIdx.x + 1) : (S >> 6);
    for (int kt = 0; kt < nkt; ++kt) {
        __syncthreads();   // all waves done with previous K/Vt/P
        {   // stage K tile [key][d]
            int c = tid;
#pragma unroll
            for (int it = 0; it < 2; ++it, c += 256) {
                const int key = c >> 3, dp = (c & 7) * 8;
                const u16* src = Kb + (tokbase + kt * 64 + key) * kvstride + h * 64 + dp;
                *(bf16x8*)(&K_lds[key * KSTR + dp]) = *(const bf16x8*)src;
            }
        }
        {   // stage V transposed [d][key]
            const int d = tid & 63, kg = tid >> 6;
            u16x8 v0, v1;
#pragma unroll
            for (int j = 0; j < 8; ++j)
                v0[j] = Vb[(tokbase + kt * 64 + kg * 16 + j) * kvstride + h * 64 + d];
#pragma unroll
            for (int j = 0; j < 8; ++j)
                v1[j] = Vb[(tokbase + kt * 64 + kg * 16 + 8 + j) * kvstride + h * 64 + d];
            *(u16x8*)(&Vt_lds[d * KSTR + kg * 16])     = v0;
            *(u16x8*)(&Vt_lds[d * KSTR + kg * 16 + 8]) = v1;
        }
        __syncthreads();

        // QK^T: D row(q) = quad*4+r, col(key) = l16
        float p[4][4];
#pragma unroll
        for (int nt = 0; nt < 4; ++nt) {
            f32x4 s = (f32x4){0.f, 0.f, 0.f, 0.f};
#pragma unroll
            for (int st = 0; st < 2; ++st) {
                bf16x8 kf = *(const bf16x8*)(&K_lds[(nt * 16 + l16) * KSTR + st * 32 + quad * 8]);
                s = __builtin_amdgcn_mfma_f32_16x16x32_bf16(qf[st], kf, s, 0, 0, 0);
            }
#pragma unroll
            for (int r = 0; r < 4; ++r) {
                float sv = s[r] * 0.125f;   // 1/sqrt(64)
                if (CAUSAL) {
                    const int qg  = qt0 + wave * 16 + quad * 4 + r;
                    const int kgi = kt * 64 + nt * 16 + l16;
                    if (kgi > qg) sv = MASKV;
                }
                p[nt][r] = sv;
            }
        }
        // online softmax (row lives in the quad's 16 lanes)
#pragma unroll
        for (int r = 0; r < 4; ++r) {
            float mx = fmaxf(fmaxf(p[0][r], p[1][r]), fmaxf(p[2][r], p[3][r]));
#pragma unroll
            for (int off = 1; off <= 8; off <<= 1) mx = fmaxf(mx, __shfl_xor(mx, off, 64));
            const float newm  = fmaxf(mrow[r], mx);
            const float alpha = __expf(mrow[r] - newm);
            float rs = 0.f;
#pragma unroll
            for (int nt = 0; nt < 4; ++nt) {
                p[nt][r] = __expf(p[nt][r] - newm);
                rs += p[nt][r];
            }
#pragma unroll
            for (int off = 1; off <= 8; off <<= 1) rs += __shfl_xor(rs, off, 64);
            lrow[r] = lrow[r] * alpha + rs;
            mrow[r] = newm;
#pragma unroll
            for (int dt = 0; dt < 4; ++dt) acc[dt][r] *= alpha;
        }
        // P -> LDS (A-operand layout [qrow][key])
#pragma unroll
        for (int nt = 0; nt < 4; ++nt)
#pragma unroll
            for (int r = 0; r < 4; ++r)
                P_lds[(wave * 16 + quad * 4 + r) * KSTR + nt * 16 + l16] = f2bf(p[nt][r]);
        __syncthreads();
        // PV: O[q][d] += P[q][key] * Vt[d][key]
#pragma unroll
        for (int st = 0; st < 2; ++st) {
            bf16x8 pf = *(const bf16x8*)(&P_lds[(wave * 16 + l16) * KSTR + st * 32 + quad * 8]);
#pragma unroll
            for (int dt = 0; dt < 4; ++dt) {
                bf16x8 vf = *(const bf16x8*)(&Vt_lds[(dt * 16 + l16) * KSTR + st * 32 + quad * 8]);
                acc[dt] = __builtin_amdgcn_mfma_f32_16x16x32_bf16(pf, vf, acc[dt], 0, 0, 0);
            }
        }
    }
#pragma unroll
    for (int r = 0; r < 4; ++r) {
        const float inv = 1.f / lrow[r];
        const long row = tokbase + qt0 + wave * 16 + quad * 4 + r;
#pragma unroll
        for (int dt = 0; dt < 4; ++dt)
            Ob[row * 1024 + h * 64 + dt * 16 + l16] = f2bf(acc[dt][r] * inv);
    }
}

// ---------------------------------------------------------------- launch
extern "C" void kernel_launch(void* const* d_in, const int* in_sizes, int n_in,
                              void* d_out, int out_size, void* d_ws, size_t ws_size,
                              hipStream_t stream) {
    u16* ws = (u16*)d_ws;
    // ---- workspace layout (u16 elements) ----
    u16* Wt_attn  = ws + 0;          // 3072x1024
    u16* Wt_self  = ws + 3145728;    // 1024x1024
    u16* Wt_q     = ws + 4194304;    // 1024x1024
    u16* Wt_kv    = ws + 5242880;    // 2048x1024
    u16* Wt_cross = ws + 7340032;    // 1024x1024
    u16* Wt_fc    = ws + 8388608;    // 4096x1024
    u16* Wt_mlp   = ws + 12582912;   // 1024x4096 (ends 16777216)
    u16* qkv      = ws + 16777216;   // 4096x3072 (dead after self-attn)
    u16* q2       = ws + 16777216;   // 4096x1024 (reuse)
    u16* kv2      = ws + 20971520;   // 4096x2048 (reuse)
    u16* x2       = ws + 16777216;   // 4096x1024 (reuse; live into MLP)
    u16* hbuf     = ws + 20971520;   // 4096x4096 (reuse; ends 37748736)
    u16* abuf     = ws + 29360128;   // 4096x1024
    u16* x1       = ws + 33554432;   // 4096x1024 (ends 37748736)
    u16* xb       = ws + 37748736;   // 4096x1024 (converted x; dead after self-proj)
    u16* y3       = ws + 37748736;   // 4096x1024 (MLP out pre-LN; reuses xb slot)
    u16* ctxb     = ws + 41943040;   // 4096x1024 (converted ctx)
    u16* P        = ws + 46137344;   // param slots
    u16* cab = P;            u16* spb = P + 4096;  u16* qb  = P + 8192;
    u16* kvb = P + 12288;    u16* cpb = P + 16384; u16* fcb = P + 20480;
    u16* mpb = P + 24576;
    u16* l1g = P + 28672;  u16* l1b = P + 32768;
    u16* l2g = P + 36864;  u16* l2b = P + 40960;
    u16* l3g = P + 45056;  u16* l3b = P + 49152;
    int* flag = (int*)(ws + 46137344 + 53248);

    const dim3 tb(256);
    const int NTOK = 4096;

    // ---- dtype sniff on x ----
    sniff_kernel<<<1, 64, 0, stream>>>((const u32*)d_in[0], flag);

    // ---- convert activations + params to bf16 ----
    cvt_kernel<<<1024, tb, 0, stream>>>(d_in[0], xb,   NTOK * 1024, flag);
    cvt_kernel<<<1024, tb, 0, stream>>>(d_in[1], ctxb, NTOK * 1024, flag);
    cvt_kernel<<<12, tb, 0, stream>>>(d_in[3],  cab, 3072, flag);
    cvt_kernel<<<4,  tb, 0, stream>>>(d_in[5],  spb, 1024, flag);
    cvt_kernel<<<4,  tb, 0, stream>>>(d_in[7],  qb,  1024, flag);
    cvt_kernel<<<8,  tb, 0, stream>>>(d_in[9],  kvb, 2048, flag);
    cvt_kernel<<<4,  tb, 0, stream>>>(d_in[11], cpb, 1024, flag);
    cvt_kernel<<<16, tb, 0, stream>>>(d_in[13], fcb, 4096, flag);
    cvt_kernel<<<4,  tb, 0, stream>>>(d_in[15], mpb, 1024, flag);
    cvt_kernel<<<4,  tb, 0, stream>>>(d_in[16], l1g, 1024, flag);
    cvt_kernel<<<4,  tb, 0, stream>>>(d_in[17], l1b, 1024, flag);
    cvt_kernel<<<4,  tb, 0, stream>>>(d_in[18], l2g, 1024, flag);
    cvt_kernel<<<4,  tb, 0, stream>>>(d_in[19], l2b, 1024, flag);
    cvt_kernel<<<4,  tb, 0, stream>>>(d_in[20], l3g, 1024, flag);
    cvt_kernel<<<4,  tb, 0, stream>>>(d_in[21], l3b, 1024, flag);

    // ---- weight transposes (+convert): W[K,N] -> Wt[N,K] ----
    transpose_cv<<<dim3(96, 32),  tb, 0, stream>>>(d_in[2],  Wt_attn,  1024, 3072, flag);
    transpose_cv<<<dim3(32, 32),  tb, 0, stream>>>(d_in[4],  Wt_self,  1024, 1024, flag);
    transpose_cv<<<dim3(32, 32),  tb, 0, stream>>>(d_in[6],  Wt_q,     1024, 1024, flag);
    transpose_cv<<<dim3(64, 32),  tb, 0, stream>>>(d_in[8],  Wt_kv,    1024, 2048, flag);
    transpose_cv<<<dim3(32, 32),  tb, 0, stream>>>(d_in[10], Wt_cross, 1024, 1024, flag);
    transpose_cv<<<dim3(128, 32), tb, 0, stream>>>(d_in[12], Wt_fc,    1024, 4096, flag);
    transpose_cv<<<dim3(32, 128), tb, 0, stream>>>(d_in[14], Wt_mlp,   4096, 1024, flag);

    // --- causal self-attention ---
    gemm_bt<0><<<dim3(24, 32), tb, 0, stream>>>(xb, Wt_attn, cab, nullptr, qkv, 3072, 1024);
    attn_kernel<true><<<dim3(16, 16, 4), tb, 0, stream>>>(qkv, qkv + 1024, qkv + 2048, abuf,
                                                          3072, 3072, 1024);
    gemm_bt<1><<<dim3(8, 32), tb, 0, stream>>>(abuf, Wt_self, spb, xb, x1, 1024, 1024);
    ln_kernel<<<NTOK, tb, 0, stream>>>(x1, l1g, l1b);

    // --- cross-attention ---
    gemm_bt<0><<<dim3(8, 32),  tb, 0, stream>>>(x1,   Wt_q,  qb,  nullptr, q2,  1024, 1024);
    gemm_bt<0><<<dim3(16, 32), tb, 0, stream>>>(ctxb, Wt_kv, kvb, nullptr, kv2, 2048, 1024);
    attn_kernel<false><<<dim3(16, 16, 4), tb, 0, stream>>>(q2, kv2, kv2 + 1024, abuf,
                                                           1024, 2048, 1024);
    gemm_bt<1><<<dim3(8, 32), tb, 0, stream>>>(abuf, Wt_cross, cpb, x1, x2, 1024, 1024);
    ln_kernel<<<NTOK, tb, 0, stream>>>(x2, l2g, l2b);

    // --- MLP ---
    gemm_bt<2><<<dim3(32, 32), tb, 0, stream>>>(x2, Wt_fc, fcb, nullptr, hbuf, 4096, 1024);
    gemm_bt<1><<<dim3(8, 32), tb, 0, stream>>>(hbuf, Wt_mlp, mpb, x2, y3, 1024, 4096);
    ln_out_kernel<<<NTOK, tb, 0, stream>>>(y3, l3g, l3b, d_out, flag);
}

// Round 4
// 651.014 us; speedup vs baseline: 1.0737x; 1.0737x over previous
//
#include <hip/hip_runtime.h>

typedef unsigned short u16;
typedef unsigned int   u32;
typedef short bf16x8 __attribute__((ext_vector_type(8)));   // 8 bf16 (4 VGPRs)
typedef unsigned short u16x8 __attribute__((ext_vector_type(8)));
typedef float f32x4 __attribute__((ext_vector_type(4)));

__device__ __forceinline__ float bf2f(u16 u) {
    u32 x = ((u32)u) << 16;
    return __builtin_bit_cast(float, x);
}
__device__ __forceinline__ u16 f2bf(float f) {
    u32 u = __builtin_bit_cast(u32, f);
    u += 0x7fffu + ((u >> 16) & 1u);   // RNE
    return (u16)(u >> 16);
}
__device__ __forceinline__ float gelu_f(float x) {
    return 0.5f * x * (1.f + tanhf(0.7978845608028654f * (x + 0.044715f * x * x * x)));
}
// async global->LDS DMA, 16 B per lane; LDS dest must be wave-uniform base (m97 path)
__device__ __forceinline__ void glds16(const u16* g, u16* l) {
    __builtin_amdgcn_global_load_lds((const __attribute__((address_space(1))) u32*)g,
                                     (__attribute__((address_space(3))) u32*)l, 16, 0, 0);
}

// ---------------------------------------------------------------- dtype sniff
__global__ void sniff_kernel(const u32* __restrict__ p, int* __restrict__ flag) {
    const int i = threadIdx.x;                    // 0..63
    const u32 w = p[i * 8191 + 5];
    const u32 e = (w >> 7) & 0xFF;
    const bool absurd = (e >= 1 && e <= 90) || (e >= 160 && e <= 254);
    const unsigned long long m = __ballot(absurd);
    if (i == 0) *flag = (__popcll(m) >= 8) ? 1 : 0;
}

// ---------------------------------------------------------------- batched convert
struct CvtPack {
    const void* src[15];
    u16*        dst[15];
    int         n[15];
};
__global__ __launch_bounds__(256) void cvt_many(CvtPack pp, const int* __restrict__ flag) {
    const int f = *flag;
    const int j = blockIdx.y;
    const void* src = pp.src[j];
    u16* dst = pp.dst[j];
    const int n = pp.n[j];
    const int idx = blockIdx.x * 256 + threadIdx.x;
    const int stride = gridDim.x * 256;
    if (f) {
        const float* s = (const float*)src;
        for (int i = idx; i < n; i += stride) dst[i] = f2bf(s[i]);
    } else {
        const u16* s = (const u16*)src;
        for (int i = idx; i < n; i += stride) dst[i] = s[i];
    }
}

// ---------------------------------------------------------------- transpose+convert
// src[Kd][Nd] (f32 or bf16 per flag) -> dst[Nd][Kd] bf16. grid (Nd/32, Kd/32).
__global__ __launch_bounds__(256) void transpose_cv(const void* __restrict__ src,
                                                    u16* __restrict__ dst,
                                                    int Kd, int Nd,
                                                    const int* __restrict__ flag) {
    const int f = *flag;
    __shared__ u16 t[32][33];
    const int tx = threadIdx.x & 31, ty = threadIdx.x >> 5;   // ty 0..7
    const int x  = blockIdx.x * 32 + tx;
    const int y0 = blockIdx.y * 32;
#pragma unroll
    for (int j = 0; j < 4; ++j) {
        const long idx = (long)(y0 + ty + j * 8) * Nd + x;
        t[ty + j * 8][tx] = f ? f2bf(((const float*)src)[idx]) : ((const u16*)src)[idx];
    }
    __syncthreads();
    const int xo = blockIdx.y * 32 + tx;
#pragma unroll
    for (int j = 0; j < 4; ++j)
        dst[(long)(blockIdx.x * 32 + ty + j * 8) * Kd + xo] = t[tx][ty + j * 8];
}

// ---------------------------------------------------------------- layernorm (in-place, bf16)
__global__ __launch_bounds__(256) void ln_kernel(u16* __restrict__ x,
                                                 const u16* __restrict__ g,
                                                 const u16* __restrict__ bta) {
    const int tid = threadIdx.x;
    u16* p = x + (long)blockIdx.x * 1024;
    float v[4];
    float s = 0.f, s2 = 0.f;
#pragma unroll
    for (int i = 0; i < 4; ++i) {
        v[i] = bf2f(p[tid + i * 256]);
        s += v[i]; s2 += v[i] * v[i];
    }
#pragma unroll
    for (int off = 32; off; off >>= 1) {
        s  += __shfl_xor(s, off, 64);
        s2 += __shfl_xor(s2, off, 64);
    }
    __shared__ float ps[8];
    if ((tid & 63) == 0) { ps[(tid >> 6) * 2] = s; ps[(tid >> 6) * 2 + 1] = s2; }
    __syncthreads();
    s  = ps[0] + ps[2] + ps[4] + ps[6];
    s2 = ps[1] + ps[3] + ps[5] + ps[7];
    const float mu  = s * (1.f / 1024.f);
    const float var = s2 * (1.f / 1024.f) - mu * mu;
    const float rs  = rsqrtf(var + 1e-5f);
#pragma unroll
    for (int i = 0; i < 4; ++i) {
        const int c = tid + i * 256;
        p[c] = f2bf((v[i] - mu) * rs * bf2f(g[c]) + bf2f(bta[c]));
    }
}

// ---------------------------------------------------------------- final layernorm
// reads bf16 xin, writes d_out as f32 (flag=1) or bf16 (flag=0).
__global__ __launch_bounds__(256) void ln_out_kernel(const u16* __restrict__ xin,
                                                     const u16* __restrict__ g,
                                                     const u16* __restrict__ bta,
                                                     void* __restrict__ out,
                                                     const int* __restrict__ flag) {
    const int tid = threadIdx.x;
    const u16* p = xin + (long)blockIdx.x * 1024;
    float v[4];
    float s = 0.f, s2 = 0.f;
#pragma unroll
    for (int i = 0; i < 4; ++i) {
        v[i] = bf2f(p[tid + i * 256]);
        s += v[i]; s2 += v[i] * v[i];
    }
#pragma unroll
    for (int off = 32; off; off >>= 1) {
        s  += __shfl_xor(s, off, 64);
        s2 += __shfl_xor(s2, off, 64);
    }
    __shared__ float ps[8];
    if ((tid & 63) == 0) { ps[(tid >> 6) * 2] = s; ps[(tid >> 6) * 2 + 1] = s2; }
    __syncthreads();
    s  = ps[0] + ps[2] + ps[4] + ps[6];
    s2 = ps[1] + ps[3] + ps[5] + ps[7];
    const float mu  = s * (1.f / 1024.f);
    const float var = s2 * (1.f / 1024.f) - mu * mu;
    const float rs  = rsqrtf(var + 1e-5f);
    const int f = *flag;
    if (f) {
        float* o = (float*)out + (long)blockIdx.x * 1024;
#pragma unroll
        for (int i = 0; i < 4; ++i) {
            const int c = tid + i * 256;
            o[c] = (v[i] - mu) * rs * bf2f(g[c]) + bf2f(bta[c]);
        }
    } else {
        u16* o = (u16*)out + (long)blockIdx.x * 1024;
#pragma unroll
        for (int i = 0; i < 4; ++i) {
            const int c = tid + i * 256;
            o[c] = f2bf((v[i] - mu) * rs * bf2f(g[c]) + bf2f(bta[c]));
        }
    }
}

// ---------------------------------------------------------------- GEMM (m97-style)
// C[M,N] = A[M,K] @ W[K,N] (+bias, +res / gelu), W pre-transposed Bt[N,K].
// BM=128 x BN (128 or 64) tile, BK=32, 4 waves, 16x16x32 MFMA.
// Staging via global_load_lds width-16 DMA into UNPADDED stride-32 LDS
// (wave-uniform chunk base + lane*16B — the m97-verified layout).
// BN=128: waves 2x2, acc[4][4].  BN=64: waves 4x1 (stacked in M), acc[2][4].
template <int BN, int EPI>    // EPI: 0 = bias, 1 = bias+residual, 2 = bias+gelu
__global__ __launch_bounds__(256) void gemm_bt(const u16* __restrict__ A,
                                               const u16* __restrict__ Bt,
                                               const u16* __restrict__ bias,
                                               const u16* __restrict__ res,
                                               u16* __restrict__ C,
                                               int N, int K) {
    constexpr int WM = (BN == 128) ? 64 : 32;      // rows per wave
    constexpr int MT = WM / 16;                    // m fragments per wave (4 or 2)
    const int tid  = threadIdx.x;
    const int wave = tid >> 6, lane = tid & 63;
    const int quad = lane >> 4, l16 = lane & 15;
    const int wm = (BN == 128) ? (wave >> 1) : wave;
    const int wn = (BN == 128) ? (wave & 1) : 0;
    const int m0 = blockIdx.y * 128, n0 = blockIdx.x * BN;

    __shared__ u16 Al[128 * 32];
    __shared__ u16 Bl[BN * 32];

    f32x4 acc[MT][4];
#pragma unroll
    for (int i = 0; i < MT; ++i)
#pragma unroll
        for (int j = 0; j < 4; ++j) acc[i][j] = (f32x4){0.f, 0.f, 0.f, 0.f};

    // DMA chunk = 16 rows x 32 k = 1024 B. lane l -> row chunk*16 + (l>>2), k (l&3)*8
    const int lrow = lane >> 2, lk = (lane & 3) * 8;

    for (int kt = 0; kt < K; kt += 32) {
        __syncthreads();                    // prev tile's LDS reads done
        glds16(A + (long)(m0 + wave * 16 + lrow) * K + kt + lk,      &Al[wave * 512]);
        glds16(A + (long)(m0 + 64 + wave * 16 + lrow) * K + kt + lk, &Al[(wave + 4) * 512]);
        glds16(Bt + (long)(n0 + wave * 16 + lrow) * K + kt + lk,     &Bl[wave * 512]);
        if constexpr (BN == 128)
            glds16(Bt + (long)(n0 + 64 + wave * 16 + lrow) * K + kt + lk,
                   &Bl[(wave + 4) * 512]);
        __syncthreads();                    // vmcnt drained -> tile staged

        bf16x8 af[MT], bfr[4];
#pragma unroll
        for (int mt = 0; mt < MT; ++mt)
            af[mt] = *(const bf16x8*)(&Al[(wm * WM + mt * 16 + l16) * 32 + quad * 8]);
#pragma unroll
        for (int nt = 0; nt < 4; ++nt)
            bfr[nt] = *(const bf16x8*)(&Bl[(wn * 64 + nt * 16 + l16) * 32 + quad * 8]);
#pragma unroll
        for (int mt = 0; mt < MT; ++mt)
#pragma unroll
            for (int nt = 0; nt < 4; ++nt)
                acc[mt][nt] = __builtin_amdgcn_mfma_f32_16x16x32_bf16(af[mt], bfr[nt],
                                                                      acc[mt][nt], 0, 0, 0);
    }

    // D row = quad*4+r, col = l16 (m89/m91-verified)
#pragma unroll
    for (int mt = 0; mt < MT; ++mt)
#pragma unroll
        for (int r = 0; r < 4; ++r) {
            const long row = m0 + wm * WM + mt * 16 + quad * 4 + r;
#pragma unroll
            for (int nt = 0; nt < 4; ++nt) {
                const int col = n0 + wn * 64 + nt * 16 + l16;
                float v = acc[mt][nt][r] + bf2f(bias[col]);
                if constexpr (EPI == 1) v += bf2f(res[row * N + col]);
                if constexpr (EPI == 2) v = gelu_f(v);
                C[row * N + col] = f2bf(v);
            }
        }
}

// ---------------------------------------------------------------- attention
// Flash-style fused attention, hd=64. One block = 64 q rows of one (b,h);
// 4 waves x 16 q rows. Output merged-heads into [tokens,1024] at col h*64.
#define KSTR 72   // 64 + 8 pad
#define MASKV -3.0e4f
template <bool CAUSAL>
__global__ __launch_bounds__(256) void attn_kernel(const u16* __restrict__ Qb,
                                                   const u16* __restrict__ Kb,
                                                   const u16* __restrict__ Vb,
                                                   u16* __restrict__ Ob,
                                                   int qstride, int kvstride, int S) {
    const int tid  = threadIdx.x;
    const int wave = tid >> 6, lane = tid & 63;
    const int quad = lane >> 4, l16 = lane & 15;
    const int h = blockIdx.y, b = blockIdx.z;
    const int qt0 = blockIdx.x * 64;
    const long tokbase = (long)b * S;

    __shared__ u16 K_lds[64 * KSTR];
    __shared__ u16 Vt_lds[64 * KSTR];   // [d][key]
    __shared__ u16 P_lds[64 * KSTR];    // [qrow(64)][key]

    // Q fragments (A-operand: m=l16, k=quad*8+j)
    const u16* qrow = Qb + (tokbase + qt0 + wave * 16 + l16) * qstride + h * 64;
    bf16x8 qf[2];
    qf[0] = *(const bf16x8*)(qrow + quad * 8);
    qf[1] = *(const bf16x8*)(qrow + 32 + quad * 8);

    f32x4 acc[4];
#pragma unroll
    for (int i = 0; i < 4; ++i) acc[i] = (f32x4){0.f, 0.f, 0.f, 0.f};
    float mrow[4], lrow[4];
#pragma unroll
    for (int r = 0; r < 4; ++r) { mrow[r] = MASKV; lrow[r] = 0.f; }

    const int nkt = CAUSAL ? (blockIdx.x + 1) : (S >> 6);
    for (int kt = 0; kt < nkt; ++kt) {
        __syncthreads();   // all waves done with previous K/Vt/P
        {   // stage K tile [key][d]
            int c = tid;
#pragma unroll
            for (int it = 0; it < 2; ++it, c += 256) {
                const int key = c >> 3, dp = (c & 7) * 8;
                const u16* src = Kb + (tokbase + kt * 64 + key) * kvstride + h * 64 + dp;
                *(bf16x8*)(&K_lds[key * KSTR + dp]) = *(const bf16x8*)src;
            }
        }
        {   // stage V transposed [d][key]
            const int d = tid & 63, kg = tid >> 6;
            u16x8 v0, v1;
#pragma unroll
            for (int j = 0; j < 8; ++j)
                v0[j] = Vb[(tokbase + kt * 64 + kg * 16 + j) * kvstride + h * 64 + d];
#pragma unroll
            for (int j = 0; j < 8; ++j)
                v1[j] = Vb[(tokbase + kt * 64 + kg * 16 + 8 + j) * kvstride + h * 64 + d];
            *(u16x8*)(&Vt_lds[d * KSTR + kg * 16])     = v0;
            *(u16x8*)(&Vt_lds[d * KSTR + kg * 16 + 8]) = v1;
        }
        __syncthreads();

        // QK^T: D row(q) = quad*4+r, col(key) = l16
        float p[4][4];
#pragma unroll
        for (int nt = 0; nt < 4; ++nt) {
            f32x4 s = (f32x4){0.f, 0.f, 0.f, 0.f};
#pragma unroll
            for (int st = 0; st < 2; ++st) {
                bf16x8 kf = *(const bf16x8*)(&K_lds[(nt * 16 + l16) * KSTR + st * 32 + quad * 8]);
                s = __builtin_amdgcn_mfma_f32_16x16x32_bf16(qf[st], kf, s, 0, 0, 0);
            }
#pragma unroll
            for (int r = 0; r < 4; ++r) {
                float sv = s[r] * 0.125f;   // 1/sqrt(64)
                if (CAUSAL) {
                    const int qg  = qt0 + wave * 16 + quad * 4 + r;
                    const int kgi = kt * 64 + nt * 16 + l16;
                    if (kgi > qg) sv = MASKV;
                }
                p[nt][r] = sv;
            }
        }
        // online softmax (row lives in the quad's 16 lanes)
#pragma unroll
        for (int r = 0; r < 4; ++r) {
            float mx = fmaxf(fmaxf(p[0][r], p[1][r]), fmaxf(p[2][r], p[3][r]));
#pragma unroll
            for (int off = 1; off <= 8; off <<= 1) mx = fmaxf(mx, __shfl_xor(mx, off, 64));
            const float newm  = fmaxf(mrow[r], mx);
            const float alpha = __expf(mrow[r] - newm);
            float rs = 0.f;
#pragma unroll
            for (int nt = 0; nt < 4; ++nt) {
                p[nt][r] = __expf(p[nt][r] - newm);
                rs += p[nt][r];
            }
#pragma unroll
            for (int off = 1; off <= 8; off <<= 1) rs += __shfl_xor(rs, off, 64);
            lrow[r] = lrow[r] * alpha + rs;
            mrow[r] = newm;
#pragma unroll
            for (int dt = 0; dt < 4; ++dt) acc[dt][r] *= alpha;
        }
        // P -> LDS (A-operand layout [qrow][key])
#pragma unroll
        for (int nt = 0; nt < 4; ++nt)
#pragma unroll
            for (int r = 0; r < 4; ++r)
                P_lds[(wave * 16 + quad * 4 + r) * KSTR + nt * 16 + l16] = f2bf(p[nt][r]);
        __syncthreads();
        // PV: O[q][d] += P[q][key] * Vt[d][key]
#pragma unroll
        for (int st = 0; st < 2; ++st) {
            bf16x8 pf = *(const bf16x8*)(&P_lds[(wave * 16 + l16) * KSTR + st * 32 + quad * 8]);
#pragma unroll
            for (int dt = 0; dt < 4; ++dt) {
                bf16x8 vf = *(const bf16x8*)(&Vt_lds[(dt * 16 + l16) * KSTR + st * 32 + quad * 8]);
                acc[dt] = __builtin_amdgcn_mfma_f32_16x16x32_bf16(pf, vf, acc[dt], 0, 0, 0);
            }
        }
    }
#pragma unroll
    for (int r = 0; r < 4; ++r) {
        const float inv = 1.f / lrow[r];
        const long row = tokbase + qt0 + wave * 16 + quad * 4 + r;
#pragma unroll
        for (int dt = 0; dt < 4; ++dt)
            Ob[row * 1024 + h * 64 + dt * 16 + l16] = f2bf(acc[dt][r] * inv);
    }
}

// ---------------------------------------------------------------- launch
extern "C" void kernel_launch(void* const* d_in, const int* in_sizes, int n_in,
                              void* d_out, int out_size, void* d_ws, size_t ws_size,
                              hipStream_t stream) {
    u16* ws = (u16*)d_ws;
    // ---- workspace layout (u16 elements) ----
    u16* Wt_attn  = ws + 0;          // 3072x1024
    u16* Wt_self  = ws + 3145728;    // 1024x1024
    u16* Wt_q     = ws + 4194304;    // 1024x1024
    u16* Wt_kv    = ws + 5242880;    // 2048x1024
    u16* Wt_cross = ws + 7340032;    // 1024x1024
    u16* Wt_fc    = ws + 8388608;    // 4096x1024
    u16* Wt_mlp   = ws + 12582912;   // 1024x4096 (ends 16777216)
    u16* qkv      = ws + 16777216;   // 4096x3072 (dead after self-attn)
    u16* q2       = ws + 16777216;   // 4096x1024 (reuse)
    u16* kv2      = ws + 20971520;   // 4096x2048 (reuse)
    u16* x2       = ws + 16777216;   // 4096x1024 (reuse; live into MLP)
    u16* hbuf     = ws + 20971520;   // 4096x4096 (reuse; ends 37748736)
    u16* abuf     = ws + 29360128;   // 4096x1024
    u16* x1       = ws + 33554432;   // 4096x1024 (ends 37748736)
    u16* xb       = ws + 37748736;   // 4096x1024 (converted x; dead after self-proj)
    u16* y3       = ws + 37748736;   // 4096x1024 (MLP out pre-LN; reuses xb slot)
    u16* ctxb     = ws + 41943040;   // 4096x1024 (converted ctx)
    u16* P        = ws + 46137344;   // param slots
    u16* cab = P;            u16* spb = P + 4096;  u16* qb  = P + 8192;
    u16* kvb = P + 12288;    u16* cpb = P + 16384; u16* fcb = P + 20480;
    u16* mpb = P + 24576;
    u16* l1g = P + 28672;  u16* l1b = P + 32768;
    u16* l2g = P + 36864;  u16* l2b = P + 40960;
    u16* l3g = P + 45056;  u16* l3b = P + 49152;
    int* flag = (int*)(ws + 46137344 + 53248);

    const dim3 tb(256);
    const int NTOK = 4096;

    // ---- dtype sniff on x ----
    sniff_kernel<<<1, 64, 0, stream>>>((const u32*)d_in[0], flag);

    // ---- convert activations + params to bf16 (single batched launch) ----
    CvtPack pp;
    pp.src[0] = d_in[0];  pp.dst[0] = xb;   pp.n[0] = NTOK * 1024;
    pp.src[1] = d_in[1];  pp.dst[1] = ctxb; pp.n[1] = NTOK * 1024;
    pp.src[2] = d_in[3];  pp.dst[2] = cab;  pp.n[2] = 3072;
    pp.src[3] = d_in[5];  pp.dst[3] = spb;  pp.n[3] = 1024;
    pp.src[4] = d_in[7];  pp.dst[4] = qb;   pp.n[4] = 1024;
    pp.src[5] = d_in[9];  pp.dst[5] = kvb;  pp.n[5] = 2048;
    pp.src[6] = d_in[11]; pp.dst[6] = cpb;  pp.n[6] = 1024;
    pp.src[7] = d_in[13]; pp.dst[7] = fcb;  pp.n[7] = 4096;
    pp.src[8] = d_in[15]; pp.dst[8] = mpb;  pp.n[8] = 1024;
    pp.src[9] = d_in[16]; pp.dst[9] = l1g;  pp.n[9] = 1024;
    pp.src[10] = d_in[17]; pp.dst[10] = l1b; pp.n[10] = 1024;
    pp.src[11] = d_in[18]; pp.dst[11] = l2g; pp.n[11] = 1024;
    pp.src[12] = d_in[19]; pp.dst[12] = l2b; pp.n[12] = 1024;
    pp.src[13] = d_in[20]; pp.dst[13] = l3g; pp.n[13] = 1024;
    pp.src[14] = d_in[21]; pp.dst[14] = l3b; pp.n[14] = 1024;
    cvt_many<<<dim3(256, 15), tb, 0, stream>>>(pp, flag);

    // ---- weight transposes (+convert): W[K,N] -> Wt[N,K] ----
    transpose_cv<<<dim3(96, 32),  tb, 0, stream>>>(d_in[2],  Wt_attn,  1024, 3072, flag);
    transpose_cv<<<dim3(32, 32),  tb, 0, stream>>>(d_in[4],  Wt_self,  1024, 1024, flag);
    transpose_cv<<<dim3(32, 32),  tb, 0, stream>>>(d_in[6],  Wt_q,     1024, 1024, flag);
    transpose_cv<<<dim3(64, 32),  tb, 0, stream>>>(d_in[8],  Wt_kv,    1024, 2048, flag);
    transpose_cv<<<dim3(32, 32),  tb, 0, stream>>>(d_in[10], Wt_cross, 1024, 1024, flag);
    transpose_cv<<<dim3(128, 32), tb, 0, stream>>>(d_in[12], Wt_fc,    1024, 4096, flag);
    transpose_cv<<<dim3(32, 128), tb, 0, stream>>>(d_in[14], Wt_mlp,   4096, 1024, flag);

    // --- causal self-attention ---
    gemm_bt<128, 0><<<dim3(24, 32), tb, 0, stream>>>(xb, Wt_attn, cab, nullptr, qkv, 3072, 1024);
    attn_kernel<true><<<dim3(16, 16, 4), tb, 0, stream>>>(qkv, qkv + 1024, qkv + 2048, abuf,
                                                          3072, 3072, 1024);
    gemm_bt<64, 1><<<dim3(16, 32), tb, 0, stream>>>(abuf, Wt_self, spb, xb, x1, 1024, 1024);
    ln_kernel<<<NTOK, tb, 0, stream>>>(x1, l1g, l1b);

    // --- cross-attention ---
    gemm_bt<64, 0><<<dim3(16, 32),  tb, 0, stream>>>(x1,   Wt_q,  qb,  nullptr, q2,  1024, 1024);
    gemm_bt<128, 0><<<dim3(16, 32), tb, 0, stream>>>(ctxb, Wt_kv, kvb, nullptr, kv2, 2048, 1024);
    attn_kernel<false><<<dim3(16, 16, 4), tb, 0, stream>>>(q2, kv2, kv2 + 1024, abuf,
                                                           1024, 2048, 1024);
    gemm_bt<64, 1><<<dim3(16, 32), tb, 0, stream>>>(abuf, Wt_cross, cpb, x1, x2, 1024, 1024);
    ln_kernel<<<NTOK, tb, 0, stream>>>(x2, l2g, l2b);

    // --- MLP ---
    gemm_bt<128, 2><<<dim3(32, 32), tb, 0, stream>>>(x2, Wt_fc, fcb, nullptr, hbuf, 4096, 1024);
    gemm_bt<64, 1><<<dim3(16, 32), tb, 0, stream>>>(hbuf, Wt_mlp, mpb, x2, y3, 1024, 4096);
    ln_out_kernel<<<NTOK, tb, 0, stream>>>(y3, l3g, l3b, d_out, flag);
}

// Round 5
// 630.351 us; speedup vs baseline: 1.1089x; 1.0328x over previous
//
#include <hip/hip_runtime.h>

typedef unsigned short u16;
typedef unsigned int   u32;
typedef short bf16x8 __attribute__((ext_vector_type(8)));   // 8 bf16 (4 VGPRs)
typedef unsigned short u16x8 __attribute__((ext_vector_type(8)));
typedef float f32x4 __attribute__((ext_vector_type(4)));

__device__ __forceinline__ float bf2f(u16 u) {
    u32 x = ((u32)u) << 16;
    return __builtin_bit_cast(float, x);
}
__device__ __forceinline__ u16 f2bf(float f) {
    u32 u = __builtin_bit_cast(u32, f);
    u += 0x7fffu + ((u >> 16) & 1u);   // RNE
    return (u16)(u >> 16);
}
__device__ __forceinline__ float gelu_f(float x) {
    return 0.5f * x * (1.f + tanhf(0.7978845608028654f * (x + 0.044715f * x * x * x)));
}
// async global->LDS DMA, 16 B per lane; LDS dest must be wave-uniform base (m97 path)
__device__ __forceinline__ void glds16(const u16* g, u16* l) {
    __builtin_amdgcn_global_load_lds((const __attribute__((address_space(1))) u32*)g,
                                     (__attribute__((address_space(3))) u32*)l, 16, 0, 0);
}

// ---------------------------------------------------------------- dtype sniff
__global__ void sniff_kernel(const u32* __restrict__ p, int* __restrict__ flag) {
    const int i = threadIdx.x;                    // 0..63
    const u32 w = p[i * 8191 + 5];
    const u32 e = (w >> 7) & 0xFF;
    const bool absurd = (e >= 1 && e <= 90) || (e >= 160 && e <= 254);
    const unsigned long long m = __ballot(absurd);
    if (i == 0) *flag = (__popcll(m) >= 8) ? 1 : 0;
}

// ---------------------------------------------------------------- batched convert
struct CvtPack {
    const void* src[15];
    u16*        dst[15];
    int         n[15];
};
__global__ __launch_bounds__(256) void cvt_many(CvtPack pp, const int* __restrict__ flag) {
    const int f = *flag;
    const int j = blockIdx.y;
    const void* src = pp.src[j];
    u16* dst = pp.dst[j];
    const int n = pp.n[j];
    const int idx = blockIdx.x * 256 + threadIdx.x;
    const int stride = gridDim.x * 256;
    if (f) {
        const float* s = (const float*)src;
        for (int i = idx; i < n; i += stride) dst[i] = f2bf(s[i]);
    } else {
        const u16* s = (const u16*)src;
        for (int i = idx; i < n; i += stride) dst[i] = s[i];
    }
}

// ---------------------------------------------------------------- transpose+convert
// src[Kd][Nd] (f32 or bf16 per flag) -> dst[Nd][Kd] bf16. grid (Nd/32, Kd/32).
__global__ __launch_bounds__(256) void transpose_cv(const void* __restrict__ src,
                                                    u16* __restrict__ dst,
                                                    int Kd, int Nd,
                                                    const int* __restrict__ flag) {
    const int f = *flag;
    __shared__ u16 t[32][33];
    const int tx = threadIdx.x & 31, ty = threadIdx.x >> 5;   // ty 0..7
    const int x  = blockIdx.x * 32 + tx;
    const int y0 = blockIdx.y * 32;
#pragma unroll
    for (int j = 0; j < 4; ++j) {
        const long idx = (long)(y0 + ty + j * 8) * Nd + x;
        t[ty + j * 8][tx] = f ? f2bf(((const float*)src)[idx]) : ((const u16*)src)[idx];
    }
    __syncthreads();
    const int xo = blockIdx.y * 32 + tx;
#pragma unroll
    for (int j = 0; j < 4; ++j)
        dst[(long)(blockIdx.x * 32 + ty + j * 8) * Kd + xo] = t[tx][ty + j * 8];
}

// ---------------------------------------------------------------- layernorm (in-place, bf16)
__global__ __launch_bounds__(256) void ln_kernel(u16* __restrict__ x,
                                                 const u16* __restrict__ g,
                                                 const u16* __restrict__ bta) {
    const int tid = threadIdx.x;
    u16* p = x + (long)blockIdx.x * 1024;
    float v[4];
    float s = 0.f, s2 = 0.f;
#pragma unroll
    for (int i = 0; i < 4; ++i) {
        v[i] = bf2f(p[tid + i * 256]);
        s += v[i]; s2 += v[i] * v[i];
    }
#pragma unroll
    for (int off = 32; off; off >>= 1) {
        s  += __shfl_xor(s, off, 64);
        s2 += __shfl_xor(s2, off, 64);
    }
    __shared__ float ps[8];
    if ((tid & 63) == 0) { ps[(tid >> 6) * 2] = s; ps[(tid >> 6) * 2 + 1] = s2; }
    __syncthreads();
    s  = ps[0] + ps[2] + ps[4] + ps[6];
    s2 = ps[1] + ps[3] + ps[5] + ps[7];
    const float mu  = s * (1.f / 1024.f);
    const float var = s2 * (1.f / 1024.f) - mu * mu;
    const float rs  = rsqrtf(var + 1e-5f);
#pragma unroll
    for (int i = 0; i < 4; ++i) {
        const int c = tid + i * 256;
        p[c] = f2bf((v[i] - mu) * rs * bf2f(g[c]) + bf2f(bta[c]));
    }
}

// ---------------------------------------------------------------- final layernorm
// reads bf16 xin, writes d_out as f32 (flag=1) or bf16 (flag=0).
__global__ __launch_bounds__(256) void ln_out_kernel(const u16* __restrict__ xin,
                                                     const u16* __restrict__ g,
                                                     const u16* __restrict__ bta,
                                                     void* __restrict__ out,
                                                     const int* __restrict__ flag) {
    const int tid = threadIdx.x;
    const u16* p = xin + (long)blockIdx.x * 1024;
    float v[4];
    float s = 0.f, s2 = 0.f;
#pragma unroll
    for (int i = 0; i < 4; ++i) {
        v[i] = bf2f(p[tid + i * 256]);
        s += v[i]; s2 += v[i] * v[i];
    }
#pragma unroll
    for (int off = 32; off; off >>= 1) {
        s  += __shfl_xor(s, off, 64);
        s2 += __shfl_xor(s2, off, 64);
    }
    __shared__ float ps[8];
    if ((tid & 63) == 0) { ps[(tid >> 6) * 2] = s; ps[(tid >> 6) * 2 + 1] = s2; }
    __syncthreads();
    s  = ps[0] + ps[2] + ps[4] + ps[6];
    s2 = ps[1] + ps[3] + ps[5] + ps[7];
    const float mu  = s * (1.f / 1024.f);
    const float var = s2 * (1.f / 1024.f) - mu * mu;
    const float rs  = rsqrtf(var + 1e-5f);
    const int f = *flag;
    if (f) {
        float* o = (float*)out + (long)blockIdx.x * 1024;
#pragma unroll
        for (int i = 0; i < 4; ++i) {
            const int c = tid + i * 256;
            o[c] = (v[i] - mu) * rs * bf2f(g[c]) + bf2f(bta[c]);
        }
    } else {
        u16* o = (u16*)out + (long)blockIdx.x * 1024;
#pragma unroll
        for (int i = 0; i < 4; ++i) {
            const int c = tid + i * 256;
            o[c] = f2bf((v[i] - mu) * rs * bf2f(g[c]) + bf2f(bta[c]));
        }
    }
}

// ---------------------------------------------------------------- GEMM (dbuf DMA K-loop)
// C[M,N] = A[M,K] @ W[K,N] (+bias, +res / gelu), W pre-transposed Bt[N,K].
// BM=128 x BN (128 or 64), BK=32, 4 waves, 16x16x32 MFMA.
// Double-buffered global_load_lds: stage tile i+1 while computing tile i;
// ONE barrier per K-iter whose vmcnt(0) drain covers a DMA that has had the
// whole compute phase to land (vs 0 cycles in the 2-barrier m97 shape).
template <int BN, int EPI>    // EPI: 0 = bias, 1 = bias+residual, 2 = bias+gelu
__global__ __launch_bounds__(256) void gemm_bt(const u16* __restrict__ A,
                                               const u16* __restrict__ Bt,
                                               const u16* __restrict__ bias,
                                               const u16* __restrict__ res,
                                               u16* __restrict__ C,
                                               int N, int K) {
    constexpr int WM = (BN == 128) ? 64 : 32;      // rows per wave
    constexpr int MT = WM / 16;                    // m fragments per wave (4 or 2)
    const int tid  = threadIdx.x;
    const int wave = tid >> 6, lane = tid & 63;
    const int quad = lane >> 4, l16 = lane & 15;
    const int wm = (BN == 128) ? (wave >> 1) : wave;
    const int wn = (BN == 128) ? (wave & 1) : 0;
    const int m0 = blockIdx.y * 128, n0 = blockIdx.x * BN;

    __shared__ u16 Al[2][128 * 32];
    __shared__ u16 Bl[2][BN * 32];

    f32x4 acc[MT][4];
#pragma unroll
    for (int i = 0; i < MT; ++i)
#pragma unroll
        for (int j = 0; j < 4; ++j) acc[i][j] = (f32x4){0.f, 0.f, 0.f, 0.f};

    // DMA chunk = 16 rows x 32 k = 1024 B. lane l -> row (l>>2), k (l&3)*8
    const int lrow = lane >> 2, lk = (lane & 3) * 8;
    const u16* Abase  = A  + (long)(m0 + wave * 16 + lrow) * K + lk;
    const u16* Abase2 = A  + (long)(m0 + 64 + wave * 16 + lrow) * K + lk;
    const u16* Bbase  = Bt + (long)(n0 + wave * 16 + lrow) * K + lk;
    const u16* Bbase2 = Bt + (long)(n0 + 64 + wave * 16 + lrow) * K + lk;

    auto stage = [&](int ib, int kt) {
        glds16(Abase + kt,  &Al[ib][wave * 512]);
        glds16(Abase2 + kt, &Al[ib][(wave + 4) * 512]);
        glds16(Bbase + kt,  &Bl[ib][wave * 512]);
        if constexpr (BN == 128)
            glds16(Bbase2 + kt, &Bl[ib][(wave + 4) * 512]);
    };

    const int nk = K >> 5;
    stage(0, 0);
    for (int i = 0; i < nk; ++i) {
        const int ib = i & 1;
        __syncthreads();                 // drains vmcnt: buf[ib] staged; prev reads done
        if (i + 1 < nk) stage(ib ^ 1, (i + 1) << 5);

        bf16x8 af[MT], bfr[4];
#pragma unroll
        for (int mt = 0; mt < MT; ++mt)
            af[mt] = *(const bf16x8*)(&Al[ib][(wm * WM + mt * 16 + l16) * 32 + quad * 8]);
#pragma unroll
        for (int nt = 0; nt < 4; ++nt)
            bfr[nt] = *(const bf16x8*)(&Bl[ib][(wn * 64 + nt * 16 + l16) * 32 + quad * 8]);
#pragma unroll
        for (int mt = 0; mt < MT; ++mt)
#pragma unroll
            for (int nt = 0; nt < 4; ++nt)
                acc[mt][nt] = __builtin_amdgcn_mfma_f32_16x16x32_bf16(af[mt], bfr[nt],
                                                                      acc[mt][nt], 0, 0, 0);
    }

    // D row = quad*4+r, col = l16 (m89/m91-verified)
#pragma unroll
    for (int mt = 0; mt < MT; ++mt)
#pragma unroll
        for (int r = 0; r < 4; ++r) {
            const long row = m0 + wm * WM + mt * 16 + quad * 4 + r;
#pragma unroll
            for (int nt = 0; nt < 4; ++nt) {
                const int col = n0 + wn * 64 + nt * 16 + l16;
                float v = acc[mt][nt][r] + bf2f(bias[col]);
                if constexpr (EPI == 1) v += bf2f(res[row * N + col]);
                if constexpr (EPI == 2) v = gelu_f(v);
                C[row * N + col] = f2bf(v);
            }
        }
}

// ---------------------------------------------------------------- attention
// Flash-style fused attention, hd=64. One block = 64 q rows of one (b,h);
// 4 waves x 16 q rows. Output merged-heads into [tokens,1024] at col h*64.
#define KSTR 72   // 64 + 8 pad
#define MASKV -3.0e4f
template <bool CAUSAL>
__global__ __launch_bounds__(256) void attn_kernel(const u16* __restrict__ Qb,
                                                   const u16* __restrict__ Kb,
                                                   const u16* __restrict__ Vb,
                                                   u16* __restrict__ Ob,
                                                   int qstride, int kvstride, int S) {
    const int tid  = threadIdx.x;
    const int wave = tid >> 6, lane = tid & 63;
    const int quad = lane >> 4, l16 = lane & 15;
    const int h = blockIdx.y, b = blockIdx.z;
    const int qt0 = blockIdx.x * 64;
    const long tokbase = (long)b * S;

    __shared__ u16 K_lds[64 * KSTR];
    __shared__ u16 Vt_lds[64 * KSTR];   // [d][key]
    __shared__ u16 P_lds[64 * KSTR];    // [qrow(64)][key]

    // Q fragments (A-operand: m=l16, k=quad*8+j)
    const u16* qrow = Qb + (tokbase + qt0 + wave * 16 + l16) * qstride + h * 64;
    bf16x8 qf[2];
    qf[0] = *(const bf16x8*)(qrow + quad * 8);
    qf[1] = *(const bf16x8*)(qrow + 32 + quad * 8);

    f32x4 acc[4];
#pragma unroll
    for (int i = 0; i < 4; ++i) acc[i] = (f32x4){0.f, 0.f, 0.f, 0.f};
    float mrow[4], lrow[4];
#pragma unroll
    for (int r = 0; r < 4; ++r) { mrow[r] = MASKV; lrow[r] = 0.f; }

    const int nkt = CAUSAL ? (blockIdx.x + 1) : (S >> 6);
    for (int kt = 0; kt < nkt; ++kt) {
        __syncthreads();   // all waves done with previous K/Vt/P
        {   // stage K tile [key][d]
            int c = tid;
#pragma unroll
            for (int it = 0; it < 2; ++it, c += 256) {
                const int key = c >> 3, dp = (c & 7) * 8;
                const u16* src = Kb + (tokbase + kt * 64 + key) * kvstride + h * 64 + dp;
                *(bf16x8*)(&K_lds[key * KSTR + dp]) = *(const bf16x8*)src;
            }
        }
        {   // stage V transposed [d][key]
            const int d = tid & 63, kg = tid >> 6;
            u16x8 v0, v1;
#pragma unroll
            for (int j = 0; j < 8; ++j)
                v0[j] = Vb[(tokbase + kt * 64 + kg * 16 + j) * kvstride + h * 64 + d];
#pragma unroll
            for (int j = 0; j < 8; ++j)
                v1[j] = Vb[(tokbase + kt * 64 + kg * 16 + 8 + j) * kvstride + h * 64 + d];
            *(u16x8*)(&Vt_lds[d * KSTR + kg * 16])     = v0;
            *(u16x8*)(&Vt_lds[d * KSTR + kg * 16 + 8]) = v1;
        }
        __syncthreads();

        // QK^T: D row(q) = quad*4+r, col(key) = l16
        float p[4][4];
#pragma unroll
        for (int nt = 0; nt < 4; ++nt) {
            f32x4 s = (f32x4){0.f, 0.f, 0.f, 0.f};
#pragma unroll
            for (int st = 0; st < 2; ++st) {
                bf16x8 kf = *(const bf16x8*)(&K_lds[(nt * 16 + l16) * KSTR + st * 32 + quad * 8]);
                s = __builtin_amdgcn_mfma_f32_16x16x32_bf16(qf[st], kf, s, 0, 0, 0);
            }
#pragma unroll
            for (int r = 0; r < 4; ++r) {
                float sv = s[r] * 0.125f;   // 1/sqrt(64)
                if (CAUSAL) {
                    const int qg  = qt0 + wave * 16 + quad * 4 + r;
                    const int kgi = kt * 64 + nt * 16 + l16;
                    if (kgi > qg) sv = MASKV;
                }
                p[nt][r] = sv;
            }
        }
        // online softmax (row lives in the quad's 16 lanes)
#pragma unroll
        for (int r = 0; r < 4; ++r) {
            float mx = fmaxf(fmaxf(p[0][r], p[1][r]), fmaxf(p[2][r], p[3][r]));
#pragma unroll
            for (int off = 1; off <= 8; off <<= 1) mx = fmaxf(mx, __shfl_xor(mx, off, 64));
            const float newm  = fmaxf(mrow[r], mx);
            const float alpha = __expf(mrow[r] - newm);
            float rs = 0.f;
#pragma unroll
            for (int nt = 0; nt < 4; ++nt) {
                p[nt][r] = __expf(p[nt][r] - newm);
                rs += p[nt][r];
            }
#pragma unroll
            for (int off = 1; off <= 8; off <<= 1) rs += __shfl_xor(rs, off, 64);
            lrow[r] = lrow[r] * alpha + rs;
            mrow[r] = newm;
#pragma unroll
            for (int dt = 0; dt < 4; ++dt) acc[dt][r] *= alpha;
        }
        // P -> LDS (A-operand layout [qrow][key])
#pragma unroll
        for (int nt = 0; nt < 4; ++nt)
#pragma unroll
            for (int r = 0; r < 4; ++r)
                P_lds[(wave * 16 + quad * 4 + r) * KSTR + nt * 16 + l16] = f2bf(p[nt][r]);
        __syncthreads();
        // PV: O[q][d] += P[q][key] * Vt[d][key]
#pragma unroll
        for (int st = 0; st < 2; ++st) {
            bf16x8 pf = *(const bf16x8*)(&P_lds[(wave * 16 + l16) * KSTR + st * 32 + quad * 8]);
#pragma unroll
            for (int dt = 0; dt < 4; ++dt) {
                bf16x8 vf = *(const bf16x8*)(&Vt_lds[(dt * 16 + l16) * KSTR + st * 32 + quad * 8]);
                acc[dt] = __builtin_amdgcn_mfma_f32_16x16x32_bf16(pf, vf, acc[dt], 0, 0, 0);
            }
        }
    }
#pragma unroll
    for (int r = 0; r < 4; ++r) {
        const float inv = 1.f / lrow[r];
        const long row = tokbase + qt0 + wave * 16 + quad * 4 + r;
#pragma unroll
        for (int dt = 0; dt < 4; ++dt)
            Ob[row * 1024 + h * 64 + dt * 16 + l16] = f2bf(acc[dt][r] * inv);
    }
}

// ---------------------------------------------------------------- launch
extern "C" void kernel_launch(void* const* d_in, const int* in_sizes, int n_in,
                              void* d_out, int out_size, void* d_ws, size_t ws_size,
                              hipStream_t stream) {
    u16* ws = (u16*)d_ws;
    // ---- workspace layout (u16 elements) ----
    u16* Wt_attn  = ws + 0;          // 3072x1024
    u16* Wt_self  = ws + 3145728;    // 1024x1024
    u16* Wt_q     = ws + 4194304;    // 1024x1024
    u16* Wt_kv    = ws + 5242880;    // 2048x1024
    u16* Wt_cross = ws + 7340032;    // 1024x1024
    u16* Wt_fc    = ws + 8388608;    // 4096x1024
    u16* Wt_mlp   = ws + 12582912;   // 1024x4096 (ends 16777216)
    u16* qkv      = ws + 16777216;   // 4096x3072 (dead after self-attn)
    u16* q2       = ws + 16777216;   // 4096x1024 (reuse)
    u16* kv2      = ws + 20971520;   // 4096x2048 (reuse)
    u16* x2       = ws + 16777216;   // 4096x1024 (reuse; live into MLP)
    u16* hbuf     = ws + 20971520;   // 4096x4096 (reuse; ends 37748736)
    u16* abuf     = ws + 29360128;   // 4096x1024
    u16* x1       = ws + 33554432;   // 4096x1024 (ends 37748736)
    u16* xb       = ws + 37748736;   // 4096x1024 (converted x; dead after self-proj)
    u16* y3       = ws + 37748736;   // 4096x1024 (MLP out pre-LN; reuses xb slot)
    u16* ctxb     = ws + 41943040;   // 4096x1024 (converted ctx)
    u16* P        = ws + 46137344;   // param slots
    u16* cab = P;            u16* spb = P + 4096;  u16* qb  = P + 8192;
    u16* kvb = P + 12288;    u16* cpb = P + 16384; u16* fcb = P + 20480;
    u16* mpb = P + 24576;
    u16* l1g = P + 28672;  u16* l1b = P + 32768;
    u16* l2g = P + 36864;  u16* l2b = P + 40960;
    u16* l3g = P + 45056;  u16* l3b = P + 49152;
    int* flag = (int*)(ws + 46137344 + 53248);

    const dim3 tb(256);
    const int NTOK = 4096;

    // ---- dtype sniff on x ----
    sniff_kernel<<<1, 64, 0, stream>>>((const u32*)d_in[0], flag);

    // ---- convert activations + params to bf16 (single batched launch) ----
    CvtPack pp;
    pp.src[0] = d_in[0];  pp.dst[0] = xb;   pp.n[0] = NTOK * 1024;
    pp.src[1] = d_in[1];  pp.dst[1] = ctxb; pp.n[1] = NTOK * 1024;
    pp.src[2] = d_in[3];  pp.dst[2] = cab;  pp.n[2] = 3072;
    pp.src[3] = d_in[5];  pp.dst[3] = spb;  pp.n[3] = 1024;
    pp.src[4] = d_in[7];  pp.dst[4] = qb;   pp.n[4] = 1024;
    pp.src[5] = d_in[9];  pp.dst[5] = kvb;  pp.n[5] = 2048;
    pp.src[6] = d_in[11]; pp.dst[6] = cpb;  pp.n[6] = 1024;
    pp.src[7] = d_in[13]; pp.dst[7] = fcb;  pp.n[7] = 4096;
    pp.src[8] = d_in[15]; pp.dst[8] = mpb;  pp.n[8] = 1024;
    pp.src[9] = d_in[16]; pp.dst[9] = l1g;  pp.n[9] = 1024;
    pp.src[10] = d_in[17]; pp.dst[10] = l1b; pp.n[10] = 1024;
    pp.src[11] = d_in[18]; pp.dst[11] = l2g; pp.n[11] = 1024;
    pp.src[12] = d_in[19]; pp.dst[12] = l2b; pp.n[12] = 1024;
    pp.src[13] = d_in[20]; pp.dst[13] = l3g; pp.n[13] = 1024;
    pp.src[14] = d_in[21]; pp.dst[14] = l3b; pp.n[14] = 1024;
    cvt_many<<<dim3(256, 15), tb, 0, stream>>>(pp, flag);

    // ---- weight transposes (+convert): W[K,N] -> Wt[N,K] ----
    transpose_cv<<<dim3(96, 32),  tb, 0, stream>>>(d_in[2],  Wt_attn,  1024, 3072, flag);
    transpose_cv<<<dim3(32, 32),  tb, 0, stream>>>(d_in[4],  Wt_self,  1024, 1024, flag);
    transpose_cv<<<dim3(32, 32),  tb, 0, stream>>>(d_in[6],  Wt_q,     1024, 1024, flag);
    transpose_cv<<<dim3(64, 32),  tb, 0, stream>>>(d_in[8],  Wt_kv,    1024, 2048, flag);
    transpose_cv<<<dim3(32, 32),  tb, 0, stream>>>(d_in[10], Wt_cross, 1024, 1024, flag);
    transpose_cv<<<dim3(128, 32), tb, 0, stream>>>(d_in[12], Wt_fc,    1024, 4096, flag);
    transpose_cv<<<dim3(32, 128), tb, 0, stream>>>(d_in[14], Wt_mlp,   4096, 1024, flag);

    // --- causal self-attention ---
    gemm_bt<128, 0><<<dim3(24, 32), tb, 0, stream>>>(xb, Wt_attn, cab, nullptr, qkv, 3072, 1024);
    attn_kernel<true><<<dim3(16, 16, 4), tb, 0, stream>>>(qkv, qkv + 1024, qkv + 2048, abuf,
                                                          3072, 3072, 1024);
    gemm_bt<64, 1><<<dim3(16, 32), tb, 0, stream>>>(abuf, Wt_self, spb, xb, x1, 1024, 1024);
    ln_kernel<<<NTOK, tb, 0, stream>>>(x1, l1g, l1b);

    // --- cross-attention ---
    gemm_bt<64, 0><<<dim3(16, 32),  tb, 0, stream>>>(x1,   Wt_q,  qb,  nullptr, q2,  1024, 1024);
    gemm_bt<128, 0><<<dim3(16, 32), tb, 0, stream>>>(ctxb, Wt_kv, kvb, nullptr, kv2, 2048, 1024);
    attn_kernel<false><<<dim3(16, 16, 4), tb, 0, stream>>>(q2, kv2, kv2 + 1024, abuf,
                                                           1024, 2048, 1024);
    gemm_bt<64, 1><<<dim3(16, 32), tb, 0, stream>>>(abuf, Wt_cross, cpb, x1, x2, 1024, 1024);
    ln_kernel<<<NTOK, tb, 0, stream>>>(x2, l2g, l2b);

    // --- MLP ---
    gemm_bt<128, 2><<<dim3(32, 32), tb, 0, stream>>>(x2, Wt_fc, fcb, nullptr, hbuf, 4096, 1024);
    gemm_bt<64, 1><<<dim3(16, 32), tb, 0, stream>>>(hbuf, Wt_mlp, mpb, x2, y3, 1024, 4096);
    ln_out_kernel<<<NTOK, tb, 0, stream>>>(y3, l3g, l3b, d_out, flag);
}